// Round 10
// baseline (221.130 us; speedup 1.0000x reference)
//
#include <hip/hip_runtime.h>
#include <hip/hip_bf16.h>
#include <stdint.h>

// Problem constants (T=128, B=64, H=1024)
#define TT 128
#define BB 64
#define HH 1024
#define MM (TT * BB)          // 8192 rows of the two GEMMs
#define NLANE (BB * HH)       // 65536 scan lanes
#define DELTA 1.0e-4          // flag band; bf16 3-pass worst-tail ~6e-5 (1.7x margin) — do NOT shrink
#define F16_ONE 0x3C00        // _Float16 1.0

typedef __attribute__((ext_vector_type(8))) short bf16x8;
typedef __attribute__((ext_vector_type(8))) _Float16 f16x8;
typedef __attribute__((ext_vector_type(4))) float f32x4;

// async global->LDS, 16 B per lane; LDS dest = wave-uniform base + lane*16
#define GLOAD16(g, l)                                                        \
    __builtin_amdgcn_global_load_lds(                                        \
        (const __attribute__((address_space(1))) unsigned int*)(g),          \
        (__attribute__((address_space(3))) unsigned int*)(l), 16, 0, 0)

#define FENCE() __builtin_amdgcn_sched_barrier(0)

static __device__ __forceinline__ unsigned short bf16_bits(float f) {
    __hip_bfloat16 b = __float2bfloat16(f);
    return *reinterpret_cast<unsigned short*>(&b);
}
static __device__ __forceinline__ unsigned short f16_bits(float f) {
    _Float16 h = (_Float16)f;
    return *reinterpret_cast<unsigned short*>(&h);
}

// ---------------------------------------------------------------------------
// Fused prep — K-concat layouts (proven):
//   A2[8192][2048] = [Xhi | Xlo] per row;  B2[1024][2048] = [W1hi | W1lo].
// ---------------------------------------------------------------------------
__global__ __launch_bounds__(256) void prep_fused(const float* __restrict__ x,
                                                  const float* __restrict__ W1,
                                                  const float* __restrict__ W2,
                                                  unsigned short* __restrict__ A2,
                                                  unsigned short* __restrict__ B2,
                                                  unsigned short* __restrict__ w2h,
                                                  int* __restrict__ cnt) {
    const int bid = blockIdx.x;
    if (bid == 0 && threadIdx.x == 0) *cnt = 0;

    if (bid < 9216) {
        const bool isX = (bid < 8192);
        const int i = (isX ? bid : bid - 8192) * 256 + threadIdx.x;
        const float4 v4 = reinterpret_cast<const float4*>(isX ? x : W1)[i];
        float v[4] = {v4.x, v4.y, v4.z, v4.w};
        unsigned short hb[4], lb[4];
#pragma unroll
        for (int c = 0; c < 4; c++) {
            hb[c] = bf16_bits(v[c]);
            __hip_bfloat16 hh = *reinterpret_cast<__hip_bfloat16*>(&hb[c]);
            lb[c] = bf16_bits(v[c] - __bfloat162float(hh));
        }
        ushort4* dst = reinterpret_cast<ushort4*>(isX ? A2 : B2);
        const int r = i >> 8;          // row (1024 cols = 256 ushort4)
        const int c4 = i & 255;
        dst[(size_t)r * 512 + c4]       = make_ushort4(hb[0], hb[1], hb[2], hb[3]);
        dst[(size_t)r * 512 + 256 + c4] = make_ushort4(lb[0], lb[1], lb[2], lb[3]);
    } else {
        const int i = (bid - 9216) * 256 + threadIdx.x;
        const float4 v4 = reinterpret_cast<const float4*>(W2)[i];
        float v[4] = {v4.x, v4.y, v4.z, v4.w};
        unsigned short hb[4];
#pragma unroll
        for (int c = 0; c < 4; c++) hb[c] = f16_bits(v[c]);
        reinterpret_cast<ushort4*>(w2h)[i] = make_ushort4(hb[0], hb[1], hb[2], hb[3]);
    }
}

// ---------------------------------------------------------------------------
// GEMM1 — R19: 128x64 WAVE TILES (4 waves, 256 thr, 1 wave/SIMD).  R18
// post-mortem: at 64x64 waves the LDS port (1920cy/tile) >= MFMA (1862cy)
// and the two pipes never overlap (MfmaUtil 42% + port 53% ~= 100%).  The
// only lever that moves the port FLOOR is wave-tile arithmetic intensity:
// 128x64 waves cut reads to 96 b128/tile/CU (1152cy) -> port 1536 < MFMA
// 1862.  At 1 wave/SIMD the VGPR budget is 512, so the full 3-pass operand
// set (Ah8+Al8+Bh4+Bl4 = 96 VGPR) + acc (128) fits with no spills and no
// reg double-buffering; read batches interleave between the three 32-MFMA
// pass clusters so ds-latency hides under MFMA trains.
//   - physical-K BK=32, 32 tiles, triple-buffered LDS (144 KB, same rows =
//     [hi 64B | lo 64B] layout + proven 8-slot XOR swizzle).
//   - staging: 12 x 4KB sub-chunks/tile (A q0..7, B b0..3; 32 rows each),
//     issued in 3 groups of 4 between clusters.  ONE vmcnt(12)+lgkmcnt(0)
//     + barrier per tile.  Ledger: at end of t outstanding = t+2's 12 =>
//     t+1 proven landed; restage target buf (t+2)%3 = (t-1)%3 whose reads
//     drained at t-1's end-of-tile lgkmcnt(0).
// ---------------------------------------------------------------------------
__global__ __launch_bounds__(256, 1) void gemm1_w128(const unsigned short* __restrict__ A2,
                                                     const unsigned short* __restrict__ B2,
                                                     float* __restrict__ C) {
    __shared__ short As_[3][256 * 64];   // 96 KB  (256 rows x 128B = hi|lo)
    __shared__ short Bs_[3][128 * 64];   // 48 KB

    const int tid = threadIdx.x;
    const int lane = tid & 63;
    const int wave = tid >> 6;       // 0..3
    const int wr = wave >> 1;        // 0..1  (M half: 128 rows)
    const int wc = wave & 1;         // 0..1  (N half: 64 cols)

    // XCD-grouped decode: blocks with same bid%8 form one XCD group of 32.
    const int bid = blockIdx.x;
    const int orig = (bid & 7) * 32 + (bid >> 3);
    const int m0 = (orig >> 3) * 256;
    const int n0 = (orig & 7) * 128;

    const int rsel = lane & 15;
    const int part = lane >> 4;      // 0..3

    // fragment LDS addresses (shorts), buffer-relative.  Row = 64 shorts =
    // 8 slots of 16B; logical slot 0..3 = hi, 4..7 = lo; physical slot =
    // logical ^ (row & 7).  lo address = hi address ^ 32 shorts (bit-2 XOR).
    int adrA[8], adrB[4];
#pragma unroll
    for (int mi = 0; mi < 8; mi++) {
        const int ra = wr * 128 + mi * 16 + rsel;
        adrA[mi] = ra * 64 + ((part ^ (ra & 7)) << 3);
    }
#pragma unroll
    for (int ni = 0; ni < 4; ni++) {
        const int rb = wc * 64 + ni * 16 + rsel;
        adrB[ni] = rb * 64 + ((part ^ (rb & 7)) << 3);
    }

    // staging: one 4KB sub-chunk (32 rows x 128B) per GLOAD16 round (256 thr
    // x 16B).  LDS linear; global source pre-swizzled (slot bit2 -> hi/lo).
    const int srow = tid >> 3;                    // 0..31 (row in sub-chunk)
    const int lsw  = (tid & 7) ^ (srow & 7);      // logical slot for this lane
    const int src_sw = (lsw & 3) * 8 + (lsw >> 2) * 1024;   // shorts
    const int ldso = wave * 512;                  // wave-uniform (shorts)

#define STAGE_A(buf, q, kc)                                                       \
    GLOAD16(&A2[(size_t)(m0 + (q) * 32 + srow) * 2048 + (kc) + src_sw],           \
            &As_[buf][(q) * 2048 + ldso])
#define STAGE_B(buf, b, kc)                                                       \
    GLOAD16(&B2[(size_t)(n0 + (b) * 32 + srow) * 2048 + (kc) + src_sw],           \
            &Bs_[buf][(b) * 2048 + ldso])
#define STAGE_G1(buf, kc)  do { STAGE_A(buf,0,kc); STAGE_A(buf,1,kc); STAGE_A(buf,2,kc); STAGE_A(buf,3,kc); } while (0)
#define STAGE_G2(buf, kc)  do { STAGE_A(buf,4,kc); STAGE_A(buf,5,kc); STAGE_A(buf,6,kc); STAGE_A(buf,7,kc); } while (0)
#define STAGE_G3(buf, kc)  do { STAGE_B(buf,0,kc); STAGE_B(buf,1,kc); STAGE_B(buf,2,kc); STAGE_B(buf,3,kc); } while (0)

    f32x4 acc[8][4] = {};

    // ---- prologue: stage tiles 0,1 (24 issues) ----
    STAGE_G1(0, 0); STAGE_G2(0, 0); STAGE_G3(0, 0);
    STAGE_G1(1, 32); STAGE_G2(1, 32); STAGE_G3(1, 32);
    asm volatile("s_waitcnt vmcnt(12)" ::: "memory");   // tile 0's 12 landed
    FENCE();
    __builtin_amdgcn_s_barrier();
    FENCE();

    int bufr = 0;   // t % 3

    for (int t = 0; t < 32; ++t) {
        const short* As = As_[bufr];
        const short* Bs = Bs_[bufr];
        const int bstg = (bufr + 2 >= 3) ? bufr - 1 : bufr + 2;   // (t+2)%3
        const int tc = (t + 2 < 32) ? t + 2 : 31;                 // clamp tail
        const int kc2 = tc * 32;

        bf16x8 aH[8], aL[8], bH[4], bL[4];

        // ---- pass-1 operand reads (Ah, Bh) ----
        aH[0] = *reinterpret_cast<const bf16x8*>(&As[adrA[0]]);
#pragma unroll
        for (int ni = 0; ni < 4; ni++)
            bH[ni] = *reinterpret_cast<const bf16x8*>(&Bs[adrB[ni]]);
#pragma unroll
        for (int mi = 1; mi < 8; mi++)
            aH[mi] = *reinterpret_cast<const bf16x8*>(&As[adrA[mi]]);
        FENCE();
        STAGE_G1(bstg, kc2);
        FENCE();

        // ---- pass 1: Ah x Bh (32 MFMA) ----
#pragma unroll
        for (int mi = 0; mi < 8; mi++)
#pragma unroll
            for (int ni = 0; ni < 4; ni++)
                acc[mi][ni] = __builtin_amdgcn_mfma_f32_16x16x32_bf16(aH[mi], bH[ni], acc[mi][ni], 0, 0, 0);
        FENCE();

        // ---- pass-2/3 operand reads (Bl, Al) ----
#pragma unroll
        for (int ni = 0; ni < 4; ni++)
            bL[ni] = *reinterpret_cast<const bf16x8*>(&Bs[adrB[ni] ^ 32]);
#pragma unroll
        for (int mi = 0; mi < 8; mi++)
            aL[mi] = *reinterpret_cast<const bf16x8*>(&As[adrA[mi] ^ 32]);
        FENCE();
        STAGE_G2(bstg, kc2);
        STAGE_G3(bstg, kc2);
        FENCE();

        // ---- pass 2: Ah x Bl (32 MFMA) ----
#pragma unroll
        for (int mi = 0; mi < 8; mi++)
#pragma unroll
            for (int ni = 0; ni < 4; ni++)
                acc[mi][ni] = __builtin_amdgcn_mfma_f32_16x16x32_bf16(aH[mi], bL[ni], acc[mi][ni], 0, 0, 0);
        FENCE();

        // ---- pass 3: Al x Bh (32 MFMA) ----
#pragma unroll
        for (int mi = 0; mi < 8; mi++)
#pragma unroll
            for (int ni = 0; ni < 4; ni++)
                acc[mi][ni] = __builtin_amdgcn_mfma_f32_16x16x32_bf16(aL[mi], bH[ni], acc[mi][ni], 0, 0, 0);
        FENCE();

        // ---- one sync point per tile ----
        asm volatile("s_waitcnt vmcnt(12) lgkmcnt(0)" ::: "memory");
        FENCE();
        __builtin_amdgcn_s_barrier();
        FENCE();

        bufr = (bufr == 2) ? 0 : bufr + 1;
    }
#undef STAGE_G1
#undef STAGE_G2
#undef STAGE_G3
#undef STAGE_A
#undef STAGE_B

    asm volatile("s_waitcnt vmcnt(0) lgkmcnt(0)" ::: "memory");   // drain tail
    FENCE();

    // ---- epilogue: C write (16x16 C/D layout: col=lane&15, row=(lane>>4)*4+r)
    const int col = lane & 15;
    const int quad = lane >> 4;
#pragma unroll
    for (int mi = 0; mi < 8; mi++)
#pragma unroll
        for (int ni = 0; ni < 4; ni++) {
            const int m = m0 + wr * 128 + mi * 16 + quad * 4;
            const int n = n0 + wc * 64 + ni * 16 + col;
            float* dst = &C[(size_t)m * HH + n];
#pragma unroll
            for (int r = 0; r < 4; r++)
                dst[(size_t)r * HH] = acc[mi][ni][r];
        }
}

// ---------------------------------------------------------------------------
// LIF scan — unchanged.
// ---------------------------------------------------------------------------
__global__ __launch_bounds__(256) void lif_scan_flag(const float* __restrict__ xp,
                                                     unsigned short* __restrict__ sp,
                                                     int* __restrict__ count,
                                                     int* __restrict__ list) {
    const int idx = blockIdx.x * 256 + threadIdx.x;
    double v = 0.0;
    bool flg = false;
#pragma unroll 4
    for (int t = 0; t < TT; t++) {
        const double x = (double)xp[(size_t)t * NLANE + idx];
        const double h = v + (x - v) * 0.5;
        const bool s = (h >= 1.0);
        flg |= (fabs(h - 1.0) < DELTA);
        v = s ? 0.0 : h;
        sp[(size_t)t * NLANE + idx] = s ? (unsigned short)F16_ONE : (unsigned short)0;
    }
    if (flg) {
        const int i = atomicAdd(count, 1);
        list[i] = idx;
    }
}

// ---------------------------------------------------------------------------
// Fused exact-recompute — unchanged.
// ---------------------------------------------------------------------------
__global__ __launch_bounds__(1024) void recompute_fused(const float* __restrict__ X,
                                                        const float* __restrict__ W1,
                                                        const int* __restrict__ count,
                                                        const int* __restrict__ list,
                                                        unsigned short* __restrict__ sp) {
    __shared__ double hbuf[TT];
    const int cnt = *count;
    const int wv = threadIdx.x >> 6;   // 0..15
    const int ln = threadIdx.x & 63;

    for (int li = blockIdx.x; li < cnt; li += gridDim.x) {
        const int lane = list[li];
        const int b = lane >> 10;
        const int h = lane & (HH - 1);
        const float4* w4 = reinterpret_cast<const float4*>(W1 + (size_t)h * HH);

        for (int t = wv; t < TT; t += 16) {
            const float4* x4 = reinterpret_cast<const float4*>(X + (size_t)(t * BB + b) * HH);
            double s0 = 0.0, s1 = 0.0, s2 = 0.0, s3 = 0.0;
#pragma unroll
            for (int i = 0; i < 4; i++) {
                const float4 xa = x4[ln + i * 64];
                const float4 wa = w4[ln + i * 64];
                s0 = fma((double)xa.x, (double)wa.x, s0);
                s1 = fma((double)xa.y, (double)wa.y, s1);
                s2 = fma((double)xa.z, (double)wa.z, s2);
                s3 = fma((double)xa.w, (double)wa.w, s3);
            }
            double s = (s0 + s1) + (s2 + s3);
#pragma unroll
            for (int off = 32; off >= 1; off >>= 1)
                s += __shfl_down(s, off);
            if (ln == 0) hbuf[t] = s;
        }
        __syncthreads();

        if (threadIdx.x == 0) {
            double v = 0.0;
            for (int t = 0; t < TT; t++) {
                const double hh = v + (hbuf[t] - v) * 0.5;
                const bool s = (hh >= 1.0);
                v = s ? 0.0 : hh;
                sp[(size_t)t * NLANE + lane] = s ? (unsigned short)F16_ONE : (unsigned short)0;
            }
        }
        __syncthreads();
    }
}

// ---------------------------------------------------------------------------
// GEMM2 — unchanged (128x64 tile, grid-transposed for S m-tile L2 reuse).
// ---------------------------------------------------------------------------
__global__ __launch_bounds__(256) void gemm2_mfma(const unsigned short* __restrict__ S,
                                                  const unsigned short* __restrict__ W,
                                                  float* __restrict__ O) {
    __shared__ short As[128 * 32];   // 8 KB
    __shared__ short Bs[64 * 32];    // 4 KB

    const int tid = threadIdx.x;
    const int lane = tid & 63;
    const int wave = tid >> 6;
    const int m0 = blockIdx.y * 128;   // 64 blocks in M (slow axis)
    const int n0 = blockIdx.x * 64;    // 16 blocks in N (fast axis)
    const int wm = (wave >> 1) * 64;   // {0,64}
    const int wn = (wave & 1) * 32;    // {0,32}

    const int rsel = lane & 15;
    const int part = lane >> 4;

    int adrA[4], adrB[2];
#pragma unroll
    for (int i = 0; i < 4; i++) {
        const int ra = wm + i * 16 + rsel;
        adrA[i] = ra * 32 + (part ^ ((ra >> 1) & 3)) * 8;
    }
#pragma unroll
    for (int i = 0; i < 2; i++) {
        const int rb = wn + i * 16 + rsel;
        adrB[i] = rb * 32 + (part ^ ((rb >> 1) & 3)) * 8;
    }

    f32x4 acc[4][2] = {};

    for (int k0 = 0; k0 < HH; k0 += 32) {
        // 768 chunks: A = 0..511, B = 512..767; wave-uniform sides (64 | 256)
#pragma unroll
        for (int p = 0; p < 3; p++) {
            const int c = tid + p * 256;
            const int cb = wave * 64 + p * 256;
            if (c < 512) {
                const int row = c >> 2;
                const int pslot = c & 3;
                const int pdata = pslot ^ ((row >> 1) & 3);
                GLOAD16(&S[(size_t)(m0 + row) * HH + k0 + pdata * 8], &As[cb * 8]);
            } else {
                const int c2 = c - 512;
                const int row = c2 >> 2;
                const int pslot = c2 & 3;
                const int pdata = pslot ^ ((row >> 1) & 3);
                GLOAD16(&W[(size_t)(n0 + row) * HH + k0 + pdata * 8], &Bs[(cb - 512) * 8]);
            }
        }
        __syncthreads();

        f16x8 a[4], b[2];
#pragma unroll
        for (int mi = 0; mi < 4; mi++)
            a[mi] = *reinterpret_cast<f16x8*>(&As[adrA[mi]]);
#pragma unroll
        for (int ni = 0; ni < 2; ni++)
            b[ni] = *reinterpret_cast<f16x8*>(&Bs[adrB[ni]]);

#pragma unroll
        for (int mi = 0; mi < 4; mi++)
#pragma unroll
            for (int ni = 0; ni < 2; ni++)
                acc[mi][ni] = __builtin_amdgcn_mfma_f32_16x16x32_f16(
                    a[mi], b[ni], acc[mi][ni], 0, 0, 0);

        __syncthreads();
    }

    const int col = lane & 15;
    const int quad = lane >> 4;
#pragma unroll
    for (int mi = 0; mi < 4; mi++)
#pragma unroll
        for (int ni = 0; ni < 2; ni++) {
            const int m = m0 + wm + mi * 16 + quad * 4;
            const int n = n0 + wn + ni * 16 + col;
            float* dst = &O[(size_t)m * HH + n];
#pragma unroll
            for (int r = 0; r < 4; r++)
                dst[(size_t)r * HH] = acc[mi][ni][r];
        }
}

// ---------------------------------------------------------------------------
// Launch (5 dispatches)
// ---------------------------------------------------------------------------
extern "C" void kernel_launch(void* const* d_in, const int* in_sizes, int n_in,
                              void* d_out, int out_size, void* d_ws, size_t ws_size,
                              hipStream_t stream) {
    const float* x  = (const float*)d_in[0];
    const float* W1 = (const float*)d_in[1];
    const float* W2 = (const float*)d_in[2];
    float* out = (float*)d_out;

    char* ws = (char*)d_ws;

    unsigned short* A2   = (unsigned short*)ws;                 // 33.55 MB  [Xhi|Xlo] 8192x2048
    unsigned short* B2   = A2 + (size_t)MM * 2048;              //  4.19 MB  [W1hi|W1lo] 1024x2048
    unsigned short* w2h  = B2 + (size_t)HH * 2048;              //  2.10 MB
    int*            list = (int*)(w2h + (size_t)HH * HH);       // 256 KB
    int*            cnt  = list + NLANE;                        // 4 B
    float*          xp   = (float*)(((uintptr_t)(cnt + 64) + 255) & ~(uintptr_t)255); // 33.55 MB
    unsigned short* sp   = (unsigned short*)ws;  // overlay: spikes reuse A2 after gemm1

    prep_fused<<<10240, 256, 0, stream>>>(x, W1, W2, A2, B2, w2h, cnt);

    gemm1_w128<<<256, 256, 0, stream>>>(A2, B2, xp);

    lif_scan_flag<<<NLANE / 256, 256, 0, stream>>>(xp, sp, cnt, list);

    recompute_fused<<<512, 1024, 0, stream>>>(x, W1, cnt, list, sp);

    dim3 g2(HH / 64, MM / 128);   // x = N (fast): 16 consecutive blocks share an S m-tile
    gemm2_mfma<<<g2, 256, 0, stream>>>(sp, w2h, out);
}

// Round 11
// 212.027 us; speedup vs baseline: 1.0429x; 1.0429x over previous
//
#include <hip/hip_runtime.h>
#include <hip/hip_bf16.h>
#include <stdint.h>

// Problem constants (T=128, B=64, H=1024)
#define TT 128
#define BB 64
#define HH 1024
#define MM (TT * BB)          // 8192 rows of the two GEMMs
#define NLANE (BB * HH)       // 65536 scan lanes
#define DELTA 1.0e-4          // flag band; bf16 3-pass worst-tail ~6e-5 (1.7x margin) — do NOT shrink
#define F16_ONE 0x3C00        // _Float16 1.0

typedef __attribute__((ext_vector_type(8))) short bf16x8;
typedef __attribute__((ext_vector_type(8))) _Float16 f16x8;
typedef __attribute__((ext_vector_type(4))) float f32x4;

// async global->LDS, 16 B per lane; LDS dest = wave-uniform base + lane*16
#define GLOAD16(g, l)                                                        \
    __builtin_amdgcn_global_load_lds(                                        \
        (const __attribute__((address_space(1))) unsigned int*)(g),          \
        (__attribute__((address_space(3))) unsigned int*)(l), 16, 0, 0)

#define FENCE() __builtin_amdgcn_sched_barrier(0)

static __device__ __forceinline__ unsigned short bf16_bits(float f) {
    __hip_bfloat16 b = __float2bfloat16(f);
    return *reinterpret_cast<unsigned short*>(&b);
}
static __device__ __forceinline__ unsigned short f16_bits(float f) {
    _Float16 h = (_Float16)f;
    return *reinterpret_cast<unsigned short*>(&h);
}

// ---------------------------------------------------------------------------
// Fused prep — K-concat layouts (proven):
//   A2[8192][2048] = [Xhi | Xlo] per row;  B2[1024][2048] = [W1hi | W1lo].
// ---------------------------------------------------------------------------
__global__ __launch_bounds__(256) void prep_fused(const float* __restrict__ x,
                                                  const float* __restrict__ W1,
                                                  const float* __restrict__ W2,
                                                  unsigned short* __restrict__ A2,
                                                  unsigned short* __restrict__ B2,
                                                  unsigned short* __restrict__ w2h,
                                                  int* __restrict__ cnt) {
    const int bid = blockIdx.x;
    if (bid == 0 && threadIdx.x == 0) *cnt = 0;

    if (bid < 9216) {
        const bool isX = (bid < 8192);
        const int i = (isX ? bid : bid - 8192) * 256 + threadIdx.x;
        const float4 v4 = reinterpret_cast<const float4*>(isX ? x : W1)[i];
        float v[4] = {v4.x, v4.y, v4.z, v4.w};
        unsigned short hb[4], lb[4];
#pragma unroll
        for (int c = 0; c < 4; c++) {
            hb[c] = bf16_bits(v[c]);
            __hip_bfloat16 hh = *reinterpret_cast<__hip_bfloat16*>(&hb[c]);
            lb[c] = bf16_bits(v[c] - __bfloat162float(hh));
        }
        ushort4* dst = reinterpret_cast<ushort4*>(isX ? A2 : B2);
        const int r = i >> 8;          // row (1024 cols = 256 ushort4)
        const int c4 = i & 255;
        dst[(size_t)r * 512 + c4]       = make_ushort4(hb[0], hb[1], hb[2], hb[3]);
        dst[(size_t)r * 512 + 256 + c4] = make_ushort4(lb[0], lb[1], lb[2], lb[3]);
    } else {
        const int i = (bid - 9216) * 256 + threadIdx.x;
        const float4 v4 = reinterpret_cast<const float4*>(W2)[i];
        float v[4] = {v4.x, v4.y, v4.z, v4.w};
        unsigned short hb[4];
#pragma unroll
        for (int c = 0; c < 4; c++) hb[c] = f16_bits(v[c]);
        reinterpret_cast<ushort4*>(w2h)[i] = make_ushort4(hb[0], hb[1], hb[2], hb[3]);
    }
}

// ---------------------------------------------------------------------------
// GEMM1 — R20: TWO INDEPENDENT 128x128 BLOCKS PER CU.  R16/R18/R19 post-
// mortems: with all waves in ONE barrier domain, ds-port (1920cy/tile/CU)
// and MFMA (1862cy) are exactly additive — no intra-block schedule broke it
// (reg pipelining, SGB interleave, intensity all ~neutral; 1 wave/SIMD
// regressed).  The untried documented mechanism is CROSS-BLOCK overlap
// (m114: independent waves on one CU overlap pipes fully; m97/m103: 912 TF
// at 128^2 with multi-block residency).  Same per-CU traffic as R18
// (128 b128 reads, 384 MFMA per tile-pair), but two barrier domains whose
// phases are unsynchronized: one block's MFMA covers the other's port/drain.
//   - 512 blocks of 256 thr (4 waves, 64x64 wave tiles), physical-K BK=32,
//     32 tiles, 3-pass hi/lo register reuse (R17, proven).
//   - double-buffered LDS 64 KB/block -> 2 blocks/CU (128 KB), 2 waves/SIMD.
//   - per tile: STAGE8(t+1) at tile start (~1800cy before its wait ->
//     latency covered), 16 ds_reads, 48 MFMA under setprio, then
//     vmcnt(0)+lgkmcnt(0)+barrier (drain covered by co-resident block).
//   - hazards: buf^1 written at t was read at t-1, drained by t-1's
//     lgkmcnt(0) before its barrier; stages(t) proven landed by t-1's
//     end-of-tile vmcnt(0).
// ---------------------------------------------------------------------------
__global__ __launch_bounds__(256, 2) void gemm1_db(const unsigned short* __restrict__ A2,
                                                   const unsigned short* __restrict__ B2,
                                                   float* __restrict__ C) {
    __shared__ short As_[2][128 * 64];   // 32 KB  (128 rows x 128B = hi|lo)
    __shared__ short Bs_[2][128 * 64];   // 32 KB

    const int tid = threadIdx.x;
    const int lane = tid & 63;
    const int wave = tid >> 6;       // 0..3
    const int wr = wave >> 1;        // 0..1  (M half: 64 rows)
    const int wc = wave & 1;         // 0..1  (N half: 64 cols)

    // XCD-grouped decode (512 blocks, 512%8==0 -> bijective): XCD x gets
    // m-panels [x*8, x*8+8) x all 8 n -> A panels L2-local per XCD.
    const int bid = blockIdx.x;
    const int orig = (bid & 7) * 64 + (bid >> 3);
    const int m0 = (orig >> 3) * 128;
    const int n0 = (orig & 7) * 128;

    const int rsel = lane & 15;
    const int part = lane >> 4;      // 0..3

    // fragment LDS addresses (shorts), buffer-relative.  Row = 64 shorts =
    // 8 slots of 16B; logical slot 0..3 = hi, 4..7 = lo; physical slot =
    // logical ^ (row & 7).  lo address = hi address ^ 32 shorts.
    int adrA[4], adrB[4];
#pragma unroll
    for (int mi = 0; mi < 4; mi++) {
        const int ra = wr * 64 + mi * 16 + rsel;
        adrA[mi] = ra * 64 + ((part ^ (ra & 7)) << 3);
    }
#pragma unroll
    for (int ni = 0; ni < 4; ni++) {
        const int rb = wc * 64 + ni * 16 + rsel;
        adrB[ni] = rb * 64 + ((part ^ (rb & 7)) << 3);
    }

    // staging: one 4KB sub-chunk (32 rows x 128B) per GLOAD16 round (256 thr
    // x 16B).  LDS linear; global source pre-swizzled (slot bit2 -> hi/lo).
    const int srow = tid >> 3;                    // 0..31 (row in sub-chunk)
    const int lsw  = (tid & 7) ^ (srow & 7);      // logical slot for this lane
    const int src_sw = (lsw & 3) * 8 + (lsw >> 2) * 1024;   // shorts
    const int ldso = wave * 512;                  // wave-uniform (shorts)

#define STAGE_A(buf, q, kc)                                                       \
    GLOAD16(&A2[(size_t)(m0 + (q) * 32 + srow) * 2048 + (kc) + src_sw],           \
            &As_[buf][(q) * 2048 + ldso])
#define STAGE_B(buf, b, kc)                                                       \
    GLOAD16(&B2[(size_t)(n0 + (b) * 32 + srow) * 2048 + (kc) + src_sw],           \
            &Bs_[buf][(b) * 2048 + ldso])
#define STAGE8(buf, kc)                                                           \
    do {                                                                          \
        STAGE_A(buf, 0, kc); STAGE_A(buf, 1, kc);                                 \
        STAGE_A(buf, 2, kc); STAGE_A(buf, 3, kc);                                 \
        STAGE_B(buf, 0, kc); STAGE_B(buf, 1, kc);                                 \
        STAGE_B(buf, 2, kc); STAGE_B(buf, 3, kc);                                 \
    } while (0)

    f32x4 acc[4][4] = {};

    // ---- prologue: stage tile 0, full drain (one-time cost) ----
    STAGE8(0, 0);
    asm volatile("s_waitcnt vmcnt(0)" ::: "memory");
    FENCE();
    __builtin_amdgcn_s_barrier();
    FENCE();

    for (int t = 0; t < 32; ++t) {
        const int buf = t & 1;
        const short* As = As_[buf];
        const short* Bs = Bs_[buf];
        const int tn = (t + 1 < 32) ? t + 1 : 31;   // clamp tail (dead data)

        // issue next tile's stages FIRST — ~full tile of compute covers HBM/L2 latency
        STAGE8(buf ^ 1, tn * 32);
        FENCE();

        // operand reads (16 b128)
        bf16x8 aH[4], aL[4], bH[4], bL[4];
#pragma unroll
        for (int mi = 0; mi < 4; mi++) {
            aH[mi] = *reinterpret_cast<const bf16x8*>(&As[adrA[mi]]);
            aL[mi] = *reinterpret_cast<const bf16x8*>(&As[adrA[mi] ^ 32]);
        }
#pragma unroll
        for (int ni = 0; ni < 4; ni++) {
            bH[ni] = *reinterpret_cast<const bf16x8*>(&Bs[adrB[ni]]);
            bL[ni] = *reinterpret_cast<const bf16x8*>(&Bs[adrB[ni] ^ 32]);
        }

        // 3-pass MFMA (48)
        __builtin_amdgcn_s_setprio(1);
#pragma unroll
        for (int mi = 0; mi < 4; mi++)
#pragma unroll
            for (int ni = 0; ni < 4; ni++) {
                acc[mi][ni] = __builtin_amdgcn_mfma_f32_16x16x32_bf16(aH[mi], bH[ni], acc[mi][ni], 0, 0, 0);
                acc[mi][ni] = __builtin_amdgcn_mfma_f32_16x16x32_bf16(aH[mi], bL[ni], acc[mi][ni], 0, 0, 0);
                acc[mi][ni] = __builtin_amdgcn_mfma_f32_16x16x32_bf16(aL[mi], bH[ni], acc[mi][ni], 0, 0, 0);
            }
        __builtin_amdgcn_s_setprio(0);

        // one sync point per tile; drain covered by the co-resident block
        asm volatile("s_waitcnt vmcnt(0) lgkmcnt(0)" ::: "memory");
        FENCE();
        __builtin_amdgcn_s_barrier();
        FENCE();
    }
#undef STAGE8
#undef STAGE_A
#undef STAGE_B

    // ---- epilogue: C write (16x16 C/D layout: col=lane&15, row=(lane>>4)*4+r)
    const int col = lane & 15;
    const int quad = lane >> 4;
#pragma unroll
    for (int mi = 0; mi < 4; mi++)
#pragma unroll
        for (int ni = 0; ni < 4; ni++) {
            const int m = m0 + wr * 64 + mi * 16 + quad * 4;
            const int n = n0 + wc * 64 + ni * 16 + col;
            float* dst = &C[(size_t)m * HH + n];
#pragma unroll
            for (int r = 0; r < 4; r++)
                dst[(size_t)r * HH] = acc[mi][ni][r];
        }
}

// ---------------------------------------------------------------------------
// LIF scan — unchanged.
// ---------------------------------------------------------------------------
__global__ __launch_bounds__(256) void lif_scan_flag(const float* __restrict__ xp,
                                                     unsigned short* __restrict__ sp,
                                                     int* __restrict__ count,
                                                     int* __restrict__ list) {
    const int idx = blockIdx.x * 256 + threadIdx.x;
    double v = 0.0;
    bool flg = false;
#pragma unroll 4
    for (int t = 0; t < TT; t++) {
        const double x = (double)xp[(size_t)t * NLANE + idx];
        const double h = v + (x - v) * 0.5;
        const bool s = (h >= 1.0);
        flg |= (fabs(h - 1.0) < DELTA);
        v = s ? 0.0 : h;
        sp[(size_t)t * NLANE + idx] = s ? (unsigned short)F16_ONE : (unsigned short)0;
    }
    if (flg) {
        const int i = atomicAdd(count, 1);
        list[i] = idx;
    }
}

// ---------------------------------------------------------------------------
// Fused exact-recompute — unchanged.
// ---------------------------------------------------------------------------
__global__ __launch_bounds__(1024) void recompute_fused(const float* __restrict__ X,
                                                        const float* __restrict__ W1,
                                                        const int* __restrict__ count,
                                                        const int* __restrict__ list,
                                                        unsigned short* __restrict__ sp) {
    __shared__ double hbuf[TT];
    const int cnt = *count;
    const int wv = threadIdx.x >> 6;   // 0..15
    const int ln = threadIdx.x & 63;

    for (int li = blockIdx.x; li < cnt; li += gridDim.x) {
        const int lane = list[li];
        const int b = lane >> 10;
        const int h = lane & (HH - 1);
        const float4* w4 = reinterpret_cast<const float4*>(W1 + (size_t)h * HH);

        for (int t = wv; t < TT; t += 16) {
            const float4* x4 = reinterpret_cast<const float4*>(X + (size_t)(t * BB + b) * HH);
            double s0 = 0.0, s1 = 0.0, s2 = 0.0, s3 = 0.0;
#pragma unroll
            for (int i = 0; i < 4; i++) {
                const float4 xa = x4[ln + i * 64];
                const float4 wa = w4[ln + i * 64];
                s0 = fma((double)xa.x, (double)wa.x, s0);
                s1 = fma((double)xa.y, (double)wa.y, s1);
                s2 = fma((double)xa.z, (double)wa.z, s2);
                s3 = fma((double)xa.w, (double)wa.w, s3);
            }
            double s = (s0 + s1) + (s2 + s3);
#pragma unroll
            for (int off = 32; off >= 1; off >>= 1)
                s += __shfl_down(s, off);
            if (ln == 0) hbuf[t] = s;
        }
        __syncthreads();

        if (threadIdx.x == 0) {
            double v = 0.0;
            for (int t = 0; t < TT; t++) {
                const double hh = v + (hbuf[t] - v) * 0.5;
                const bool s = (hh >= 1.0);
                v = s ? 0.0 : hh;
                sp[(size_t)t * NLANE + lane] = s ? (unsigned short)F16_ONE : (unsigned short)0;
            }
        }
        __syncthreads();
    }
}

// ---------------------------------------------------------------------------
// GEMM2 — unchanged (128x64 tile, grid-transposed for S m-tile L2 reuse).
// ---------------------------------------------------------------------------
__global__ __launch_bounds__(256) void gemm2_mfma(const unsigned short* __restrict__ S,
                                                  const unsigned short* __restrict__ W,
                                                  float* __restrict__ O) {
    __shared__ short As[128 * 32];   // 8 KB
    __shared__ short Bs[64 * 32];    // 4 KB

    const int tid = threadIdx.x;
    const int lane = tid & 63;
    const int wave = tid >> 6;
    const int m0 = blockIdx.y * 128;   // 64 blocks in M (slow axis)
    const int n0 = blockIdx.x * 64;    // 16 blocks in N (fast axis)
    const int wm = (wave >> 1) * 64;   // {0,64}
    const int wn = (wave & 1) * 32;    // {0,32}

    const int rsel = lane & 15;
    const int part = lane >> 4;

    int adrA[4], adrB[2];
#pragma unroll
    for (int i = 0; i < 4; i++) {
        const int ra = wm + i * 16 + rsel;
        adrA[i] = ra * 32 + (part ^ ((ra >> 1) & 3)) * 8;
    }
#pragma unroll
    for (int i = 0; i < 2; i++) {
        const int rb = wn + i * 16 + rsel;
        adrB[i] = rb * 32 + (part ^ ((rb >> 1) & 3)) * 8;
    }

    f32x4 acc[4][2] = {};

    for (int k0 = 0; k0 < HH; k0 += 32) {
        // 768 chunks: A = 0..511, B = 512..767; wave-uniform sides (64 | 256)
#pragma unroll
        for (int p = 0; p < 3; p++) {
            const int c = tid + p * 256;
            const int cb = wave * 64 + p * 256;
            if (c < 512) {
                const int row = c >> 2;
                const int pslot = c & 3;
                const int pdata = pslot ^ ((row >> 1) & 3);
                GLOAD16(&S[(size_t)(m0 + row) * HH + k0 + pdata * 8], &As[cb * 8]);
            } else {
                const int c2 = c - 512;
                const int row = c2 >> 2;
                const int pslot = c2 & 3;
                const int pdata = pslot ^ ((row >> 1) & 3);
                GLOAD16(&W[(size_t)(n0 + row) * HH + k0 + pdata * 8], &Bs[(cb - 512) * 8]);
            }
        }
        __syncthreads();

        f16x8 a[4], b[2];
#pragma unroll
        for (int mi = 0; mi < 4; mi++)
            a[mi] = *reinterpret_cast<f16x8*>(&As[adrA[mi]]);
#pragma unroll
        for (int ni = 0; ni < 2; ni++)
            b[ni] = *reinterpret_cast<f16x8*>(&Bs[adrB[ni]]);

#pragma unroll
        for (int mi = 0; mi < 4; mi++)
#pragma unroll
            for (int ni = 0; ni < 2; ni++)
                acc[mi][ni] = __builtin_amdgcn_mfma_f32_16x16x32_f16(
                    a[mi], b[ni], acc[mi][ni], 0, 0, 0);

        __syncthreads();
    }

    const int col = lane & 15;
    const int quad = lane >> 4;
#pragma unroll
    for (int mi = 0; mi < 4; mi++)
#pragma unroll
        for (int ni = 0; ni < 2; ni++) {
            const int m = m0 + wm + mi * 16 + quad * 4;
            const int n = n0 + wn + ni * 16 + col;
            float* dst = &O[(size_t)m * HH + n];
#pragma unroll
            for (int r = 0; r < 4; r++)
                dst[(size_t)r * HH] = acc[mi][ni][r];
        }
}

// ---------------------------------------------------------------------------
// Launch (5 dispatches)
// ---------------------------------------------------------------------------
extern "C" void kernel_launch(void* const* d_in, const int* in_sizes, int n_in,
                              void* d_out, int out_size, void* d_ws, size_t ws_size,
                              hipStream_t stream) {
    const float* x  = (const float*)d_in[0];
    const float* W1 = (const float*)d_in[1];
    const float* W2 = (const float*)d_in[2];
    float* out = (float*)d_out;

    char* ws = (char*)d_ws;

    unsigned short* A2   = (unsigned short*)ws;                 // 33.55 MB  [Xhi|Xlo] 8192x2048
    unsigned short* B2   = A2 + (size_t)MM * 2048;              //  4.19 MB  [W1hi|W1lo] 1024x2048
    unsigned short* w2h  = B2 + (size_t)HH * 2048;              //  2.10 MB
    int*            list = (int*)(w2h + (size_t)HH * HH);       // 256 KB
    int*            cnt  = list + NLANE;                        // 4 B
    float*          xp   = (float*)(((uintptr_t)(cnt + 64) + 255) & ~(uintptr_t)255); // 33.55 MB
    unsigned short* sp   = (unsigned short*)ws;  // overlay: spikes reuse A2 after gemm1

    prep_fused<<<10240, 256, 0, stream>>>(x, W1, W2, A2, B2, w2h, cnt);

    gemm1_db<<<512, 256, 0, stream>>>(A2, B2, xp);

    lif_scan_flag<<<NLANE / 256, 256, 0, stream>>>(xp, sp, cnt, list);

    recompute_fused<<<512, 1024, 0, stream>>>(x, W1, cnt, list, sp);

    dim3 g2(HH / 64, MM / 128);   // x = N (fast): 16 consecutive blocks share an S m-tile
    gemm2_mfma<<<g2, 256, 0, stream>>>(sp, w2h, out);
}